// Round 1
// baseline (1029.933 us; speedup 1.0000x reference)
//
#include <hip/hip_runtime.h>
#include <math.h>

#define BB 8
#define LL 2048
#define DD 128
#define HH 4
#define DKK 32
#define DFFF 256

static __constant__ const float NEGMIN_ = -3.402823466e38f;
#define NEGMIN (-3.402823466e38f)

// ---------------- QKV projection ----------------
// grid: (B*L)/16 blocks, 384 threads. Each block: 16 rows of x in LDS,
// thread t -> (sel, h, e) output column; 16 accumulators over d.
__global__ __launch_bounds__(384) void qkv_kernel(
    const float* __restrict__ x,
    const float* __restrict__ Wq, const float* __restrict__ Wk,
    const float* __restrict__ Wv,
    float* __restrict__ q, float* __restrict__ k, float* __restrict__ v) {
  __shared__ float xs[16][128];
  const int t = threadIdx.x;
  const long r0 = (long)blockIdx.x * 16;
  for (int idx = t; idx < 16 * 128; idx += 384)
    xs[idx >> 7][idx & 127] = x[r0 * 128 + idx];
  __syncthreads();

  const int sel = t >> 7;       // 0=q 1=k 2=v
  const int jj = t & 127;
  const int h = jj >> 5, e = jj & 31;
  const float* W = (sel == 0) ? Wq : (sel == 1) ? Wk : Wv;
  const float* Wbase = W + (h * 128) * 32 + e;   // [H,D,DK]
  float acc[16];
#pragma unroll
  for (int r = 0; r < 16; ++r) acc[r] = 0.f;
  for (int d = 0; d < 128; ++d) {
    const float w = Wbase[d * 32];
#pragma unroll
    for (int r = 0; r < 16; ++r) acc[r] += xs[r][d] * w;
  }
  float* out = (sel == 0) ? q : (sel == 1) ? k : v;
  const int b = (int)(r0 >> 11);     // L=2048 rows per batch
  const int l0 = (int)(r0 & 2047);
#pragma unroll
  for (int r = 0; r < 16; ++r)
    out[(((long)(b * HH + h)) * LL + (l0 + r)) * DKK + e] = acc[r];
}

// ---------------- Flash attention ----------------
// grid: (L/32, B*H), 256 threads (4 waves). wave handles 8 q-rows,
// 8 lanes per row (j = lane&7). K/V tiles of 64 rows in LDS (pad 36).
__global__ __launch_bounds__(256) void attn_kernel(
    const float* __restrict__ q, const float* __restrict__ k,
    const float* __restrict__ v, const float* __restrict__ mask,
    float* __restrict__ o) {
  const int qt = blockIdx.x;   // 0..63
  const int bh = blockIdx.y;   // 0..31
  const int b = bh >> 2;
  const int h = bh & 3;
  __shared__ float Qs[32][36];
  __shared__ float Ks[64][36];
  __shared__ float Vs[64][36];
  __shared__ float Ps[32][66];
  __shared__ float mks[64];
  const int t = threadIdx.x;
  const int q0 = qt * 32;
  const float* qb = q + ((long)bh * LL + q0) * DKK;
  {
    const int row = t >> 3, c = t & 7;
    float4 v4 = *(const float4*)(qb + row * DKK + c * 4);
    Qs[row][c * 4 + 0] = v4.x; Qs[row][c * 4 + 1] = v4.y;
    Qs[row][c * 4 + 2] = v4.z; Qs[row][c * 4 + 3] = v4.w;
  }
  __syncthreads();
  const int wave = t >> 6, lane = t & 63;
  const int r = lane >> 3, j = lane & 7;
  const int qr = wave * 8 + r;
  float qreg[32];
#pragma unroll
  for (int d = 0; d < 32; ++d) qreg[d] = Qs[qr][d];
  const float mq = mask[b * LL + q0 + qr];
  float m = -INFINITY, lsum = 0.f;
  float4 oacc = make_float4(0.f, 0.f, 0.f, 0.f);
  const float* kb = k + (long)bh * LL * DKK;
  const float* vb = v + (long)bh * LL * DKK;

  for (int kt = 0; kt < LL / 64; ++kt) {
    const int k0 = kt * 64;
    __syncthreads();
#pragma unroll
    for (int it = 0; it < 2; ++it) {
      const int idx = t + it * 256;
      const int row = idx >> 3, c = idx & 7;
      float4 k4 = *(const float4*)(kb + (long)(k0 + row) * DKK + c * 4);
      Ks[row][c * 4 + 0] = k4.x; Ks[row][c * 4 + 1] = k4.y;
      Ks[row][c * 4 + 2] = k4.z; Ks[row][c * 4 + 3] = k4.w;
      float4 v4 = *(const float4*)(vb + (long)(k0 + row) * DKK + c * 4);
      Vs[row][c * 4 + 0] = v4.x; Vs[row][c * 4 + 1] = v4.y;
      Vs[row][c * 4 + 2] = v4.z; Vs[row][c * 4 + 3] = v4.w;
    }
    if (t < 64) mks[t] = mask[b * LL + k0 + t];
    __syncthreads();

    float logit[8];
    float tmax = -INFINITY;
#pragma unroll
    for (int t8 = 0; t8 < 8; ++t8) {
      const int kk = j + t8 * 8;
      float acc = 0.f;
#pragma unroll
      for (int d4 = 0; d4 < 8; ++d4) {
        float4 kv = *(const float4*)&Ks[kk][d4 * 4];
        acc += qreg[d4 * 4 + 0] * kv.x + qreg[d4 * 4 + 1] * kv.y +
               qreg[d4 * 4 + 2] * kv.z + qreg[d4 * 4 + 3] * kv.w;
      }
      acc += (1.f - mq * mks[kk]) * NEGMIN;
      logit[t8] = acc;
      tmax = fmaxf(tmax, acc);
    }
    tmax = fmaxf(tmax, __shfl_xor(tmax, 1));
    tmax = fmaxf(tmax, __shfl_xor(tmax, 2));
    tmax = fmaxf(tmax, __shfl_xor(tmax, 4));
    const float m_new = fmaxf(m, tmax);
    const float scale = __expf(m - m_new);
    float psum = 0.f;
#pragma unroll
    for (int t8 = 0; t8 < 8; ++t8) {
      const int kk = j + t8 * 8;
      const float p = __expf(logit[t8] - m_new);
      psum += p;
      Ps[qr][kk] = p;
    }
    psum += __shfl_xor(psum, 1);
    psum += __shfl_xor(psum, 2);
    psum += __shfl_xor(psum, 4);
    lsum = lsum * scale + psum;
    m = m_new;
    oacc.x *= scale; oacc.y *= scale; oacc.z *= scale; oacc.w *= scale;
    __syncthreads();   // P visible to whole row-group (same wave, but safe)
#pragma unroll 8
    for (int kk = 0; kk < 64; ++kk) {
      const float p = Ps[qr][kk];
      float4 vv = *(const float4*)&Vs[kk][j * 4];
      oacc.x += p * vv.x; oacc.y += p * vv.y;
      oacc.z += p * vv.z; oacc.w += p * vv.w;
    }
  }
  const float rdiv = 1.f / lsum;
  float4 res = make_float4(oacc.x * rdiv, oacc.y * rdiv, oacc.z * rdiv,
                           oacc.w * rdiv);
  *(float4*)(o + ((long)b * LL + q0 + qr) * DD + h * DKK + j * 4) = res;
}

// ---------------- output projection + residual ----------------
__global__ __launch_bounds__(256) void oproj_kernel(
    const float* __restrict__ o, const float* __restrict__ x,
    const float* __restrict__ Wo, float* __restrict__ xmid) {
  __shared__ float os[16][128];
  const int t = threadIdx.x;
  const long r0 = (long)blockIdx.x * 16;
  for (int idx = t; idx < 2048; idx += 256)
    os[idx >> 7][idx & 127] = o[r0 * 128 + idx];
  __syncthreads();
  const int jj = t & 127, rh = t >> 7;
  float acc[8];
#pragma unroll
  for (int r = 0; r < 8; ++r) acc[r] = 0.f;
  for (int d = 0; d < 128; ++d) {
    const float w = Wo[d * 128 + jj];
#pragma unroll
    for (int r = 0; r < 8; ++r) acc[r] += os[rh * 8 + r][d] * w;
  }
#pragma unroll
  for (int r = 0; r < 8; ++r) {
    const long gr = r0 + rh * 8 + r;
    xmid[gr * 128 + jj] = (acc[r] + x[gr * 128 + jj]) * 0.5f;
  }
}

// ---------------- FFN layer 1 + exact GELU ----------------
__global__ __launch_bounds__(256) void ffn1_kernel(
    const float* __restrict__ xmid, const float* __restrict__ W1,
    const float* __restrict__ b1, float* __restrict__ f) {
  __shared__ float xs[16][128];
  const int t = threadIdx.x;
  const long r0 = (long)blockIdx.x * 16;
  for (int idx = t; idx < 2048; idx += 256)
    xs[idx >> 7][idx & 127] = xmid[r0 * 128 + idx];
  __syncthreads();
  float acc[16];
#pragma unroll
  for (int r = 0; r < 16; ++r) acc[r] = 0.f;
  for (int d = 0; d < 128; ++d) {
    const float w = W1[d * 256 + t];
#pragma unroll
    for (int r = 0; r < 16; ++r) acc[r] += xs[r][d] * w;
  }
  const float bj = b1[t];
#pragma unroll
  for (int r = 0; r < 16; ++r) {
    const float val = acc[r] + bj;
    const float g = 0.5f * val * (1.f + erff(val * 0.70710678118654752f));
    f[(r0 + r) * 256 + t] = g;
  }
}

// ---------------- FFN layer 2 + bias + residual ----------------
__global__ __launch_bounds__(256) void ffn2_kernel(
    const float* __restrict__ f, const float* __restrict__ xmid,
    const float* __restrict__ W2, const float* __restrict__ b2,
    float* __restrict__ xout) {
  __shared__ float fs[16][256];
  const int t = threadIdx.x;
  const long r0 = (long)blockIdx.x * 16;
  for (int idx = t; idx < 4096; idx += 256)
    fs[idx >> 8][idx & 255] = f[r0 * 256 + idx];
  __syncthreads();
  const int jj = t & 127, rh = t >> 7;
  float acc[8];
#pragma unroll
  for (int r = 0; r < 8; ++r) acc[r] = 0.f;
  for (int d = 0; d < 256; ++d) {
    const float w = W2[d * 128 + jj];
#pragma unroll
    for (int r = 0; r < 8; ++r) acc[r] += fs[rh * 8 + r][d] * w;
  }
  const float bj = b2[jj];
#pragma unroll
  for (int r = 0; r < 8; ++r) {
    const long gr = r0 + rh * 8 + r;
    xout[gr * 128 + jj] = (acc[r] + bj + xmid[gr * 128 + jj]) * 0.5f;
  }
}

extern "C" void kernel_launch(void* const* d_in, const int* in_sizes, int n_in,
                              void* d_out, int out_size, void* d_ws,
                              size_t ws_size, hipStream_t stream) {
  const float* x    = (const float*)d_in[0];
  const float* mask = (const float*)d_in[1];
  const float* Wq   = (const float*)d_in[2];
  const float* Wk   = (const float*)d_in[3];
  const float* Wv   = (const float*)d_in[4];
  const float* Wo   = (const float*)d_in[5];
  const float* W1   = (const float*)d_in[6];
  const float* b1   = (const float*)d_in[7];
  const float* W2   = (const float*)d_in[8];
  const float* b2   = (const float*)d_in[9];

  const long SZ = (long)BB * LL * DD;   // 2,097,152 floats
  float* ws = (float*)d_ws;
  float* qb   = ws;            // B*H*L*DK == SZ
  float* kb   = ws + SZ;
  float* vb   = ws + 2 * SZ;
  float* ob   = ws + 3 * SZ;
  float* xmid = ws + 4 * SZ;
  float* fb   = ws + 5 * SZ;   // B*L*DFF == 2*SZ  (aliases nothing live)
  float* xA   = ws + 7 * SZ;

  const int M = BB * LL;       // 16384 rows
  const int rowBlocks = M / 16;

  for (int i = 0; i < 2; ++i) {
    const float* xin = (i == 0) ? x : xA;
    float* xout = (i == 1) ? (float*)d_out : xA;
    const float* Wq_i = Wq + (long)i * HH * DD * DKK;   // 16384
    const float* Wk_i = Wk + (long)i * HH * DD * DKK;
    const float* Wv_i = Wv + (long)i * HH * DD * DKK;
    const float* Wo_i = Wo + (long)i * DD * DD;          // 16384
    const float* W1_i = W1 + (long)i * DD * DFFF;        // 32768
    const float* b1_i = b1 + (long)i * DFFF;
    const float* W2_i = W2 + (long)i * DFFF * DD;        // 32768
    const float* b2_i = b2 + (long)i * DD;

    qkv_kernel<<<rowBlocks, 384, 0, stream>>>(xin, Wq_i, Wk_i, Wv_i, qb, kb, vb);
    attn_kernel<<<dim3(LL / 32, BB * HH), 256, 0, stream>>>(qb, kb, vb, mask, ob);
    oproj_kernel<<<rowBlocks, 256, 0, stream>>>(ob, xin, Wo_i, xmid);
    ffn1_kernel<<<rowBlocks, 256, 0, stream>>>(xmid, W1_i, b1_i, fb);
    ffn2_kernel<<<rowBlocks, 256, 0, stream>>>(fb, xmid, W2_i, b2_i, xout);
  }
}

// Round 2
// 430.223 us; speedup vs baseline: 2.3940x; 2.3940x over previous
//
#include <hip/hip_runtime.h>
#include <math.h>

#define BB 8
#define LL 2048
#define DD 128
#define HH 4
#define DKK 32
#define DFFF 256

#define NEGMIN (-3.402823466e38f)

typedef _Float16 f16;
typedef _Float16 f16x8 __attribute__((ext_vector_type(8)));
typedef float f32x4 __attribute__((ext_vector_type(4)));

// ---------------- QKV projection (f32 in -> f16 q,k + f16 transposed v) ----
// grid: (B*L)/16 blocks, 384 threads. Each block: 16 rows of x in LDS,
// thread t -> (sel, h, e) output column; 16 accumulators over d.
__global__ __launch_bounds__(384) void qkv_kernel(
    const float* __restrict__ x,
    const float* __restrict__ Wq, const float* __restrict__ Wk,
    const float* __restrict__ Wv,
    f16* __restrict__ qh, f16* __restrict__ kh, f16* __restrict__ vth) {
  __shared__ float xs[16][128];
  const int t = threadIdx.x;
  const long r0 = (long)blockIdx.x * 16;
  for (int idx = t; idx < 16 * 128; idx += 384)
    xs[idx >> 7][idx & 127] = x[r0 * 128 + idx];
  __syncthreads();

  const int sel = t >> 7;       // 0=q 1=k 2=v
  const int jj = t & 127;
  const int h = jj >> 5, e = jj & 31;
  const float* W = (sel == 0) ? Wq : (sel == 1) ? Wk : Wv;
  const float* Wbase = W + (h * 128) * 32 + e;   // [H,D,DK]
  float acc[16];
#pragma unroll
  for (int r = 0; r < 16; ++r) acc[r] = 0.f;
  for (int d = 0; d < 128; ++d) {
    const float w = Wbase[d * 32];
#pragma unroll
    for (int r = 0; r < 16; ++r) acc[r] += xs[r][d] * w;
  }
  const int b = (int)(r0 >> 11);     // L=2048 rows per batch
  const int l0 = (int)(r0 & 2047);
  const int bh = b * HH + h;
  if (sel == 2) {
    // transposed: vth[bh][e][l]
    f16 tmp[16];
#pragma unroll
    for (int r = 0; r < 16; ++r) tmp[r] = (f16)acc[r];
    f16* base = vth + ((size_t)bh * DKK + e) * LL + l0;
    *(f16x8*)(base) = *(f16x8*)&tmp[0];
    *(f16x8*)(base + 8) = *(f16x8*)&tmp[8];
  } else {
    f16* out = (sel == 0) ? qh : kh;
#pragma unroll
    for (int r = 0; r < 16; ++r)
      out[((size_t)bh * LL + (l0 + r)) * DKK + e] = (f16)acc[r];
  }
}

// ---------------- Flash attention via f16 MFMA ----------------
// grid: (L/128, B*H), 256 threads (4 waves). Wave handles 32 q-rows
// (2 M-tiles of 16). KV tiles of 64 staged in LDS with padded rows.
__global__ __launch_bounds__(256) void attn_kernel(
    const f16* __restrict__ qh, const f16* __restrict__ kh,
    const f16* __restrict__ vth, const float* __restrict__ mask,
    float* __restrict__ o) {
  __shared__ f16 Ks[64][40];     // 64 kv rows x 32 d (pad->40)
  __shared__ f16 Vt[32][72];     // 32 d rows x 64 kv (pad->72)
  __shared__ f16 Ps[4][32][72];  // per-wave P tiles, 32 q x 64 k (pad->72)
  __shared__ float mks[64];
  const int t = threadIdx.x;
  const int wave = t >> 6, lane = t & 63;
  const int g = lane >> 4, c = lane & 15;
  const int bh = blockIdx.y;
  const int b = bh >> 2;
  const int qw = blockIdx.x * 128 + wave * 32;   // wave's q base

  // Q fragments (A operand), held in registers for the whole kernel
  f16x8 qfrag[2];
#pragma unroll
  for (int mt = 0; mt < 2; ++mt)
    qfrag[mt] = *(const f16x8*)(qh + ((size_t)bh * LL + qw + mt * 16 + c) * DKK + g * 8);

  // per-row mask values (row = g*4+reg within each M-tile)
  float mqv[2][4];
#pragma unroll
  for (int mt = 0; mt < 2; ++mt)
#pragma unroll
    for (int r = 0; r < 4; ++r)
      mqv[mt][r] = mask[b * LL + qw + mt * 16 + g * 4 + r];

  f32x4 o4[2][2];
  float m[2][4], l[2][4];
#pragma unroll
  for (int mt = 0; mt < 2; ++mt)
#pragma unroll
    for (int dt = 0; dt < 2; ++dt)
#pragma unroll
      for (int r = 0; r < 4; ++r) o4[mt][dt][r] = 0.f;
#pragma unroll
  for (int mt = 0; mt < 2; ++mt)
#pragma unroll
    for (int r = 0; r < 4; ++r) { m[mt][r] = -3.0e38f; l[mt][r] = 0.f; }

  const f16* kbase = kh + (size_t)bh * LL * DKK;
  const f16* vbase = vth + (size_t)bh * DKK * LL;

  for (int kt = 0; kt < LL / 64; ++kt) {
    const int k0 = kt * 64;
    __syncthreads();
    {
      const int row = t >> 2, ch = t & 3;
      *(f16x8*)&Ks[row][ch * 8] =
          *(const f16x8*)(kbase + (size_t)(k0 + row) * DKK + ch * 8);
      const int vd = t >> 3, seg = t & 7;
      *(f16x8*)&Vt[vd][seg * 8] =
          *(const f16x8*)(vbase + (size_t)vd * LL + k0 + seg * 8);
      if (t < 64) mks[t] = mask[b * LL + k0 + t];
    }
    __syncthreads();

    // ---- QK^T: S[q][k] tiles ----
    f16x8 kb[4];
#pragma unroll
    for (int nt = 0; nt < 4; ++nt)
      kb[nt] = *(const f16x8*)&Ks[c + nt * 16][g * 8];

    f32x4 s[2][4];
#pragma unroll
    for (int mt = 0; mt < 2; ++mt)
#pragma unroll
      for (int nt = 0; nt < 4; ++nt) {
        f32x4 z = {0.f, 0.f, 0.f, 0.f};
        s[mt][nt] = __builtin_amdgcn_mfma_f32_16x16x32_f16(qfrag[mt], kb[nt], z, 0, 0, 0);
      }

    // mask add
    float mkv[4];
#pragma unroll
    for (int nt = 0; nt < 4; ++nt) mkv[nt] = mks[c + nt * 16];
#pragma unroll
    for (int mt = 0; mt < 2; ++mt)
#pragma unroll
      for (int nt = 0; nt < 4; ++nt)
#pragma unroll
        for (int r = 0; r < 4; ++r)
          s[mt][nt][r] += (1.f - mqv[mt][r] * mkv[nt]) * NEGMIN;

    // ---- online softmax ----
#pragma unroll
    for (int mt = 0; mt < 2; ++mt)
#pragma unroll
      for (int r = 0; r < 4; ++r) {
        float vmax = fmaxf(fmaxf(s[mt][0][r], s[mt][1][r]),
                           fmaxf(s[mt][2][r], s[mt][3][r]));
        vmax = fmaxf(vmax, __shfl_xor(vmax, 1));
        vmax = fmaxf(vmax, __shfl_xor(vmax, 2));
        vmax = fmaxf(vmax, __shfl_xor(vmax, 4));
        vmax = fmaxf(vmax, __shfl_xor(vmax, 8));
        const float mn = fmaxf(m[mt][r], vmax);
        const float sc = __expf(m[mt][r] - mn);
        float ps = 0.f;
#pragma unroll
        for (int nt = 0; nt < 4; ++nt) {
          const float p = __expf(s[mt][nt][r] - mn);
          ps += p;
          Ps[wave][mt * 16 + g * 4 + r][c + nt * 16] = (f16)p;
        }
        ps += __shfl_xor(ps, 1);
        ps += __shfl_xor(ps, 2);
        ps += __shfl_xor(ps, 4);
        ps += __shfl_xor(ps, 8);
        l[mt][r] = l[mt][r] * sc + ps;
        m[mt][r] = mn;
#pragma unroll
        for (int dt = 0; dt < 2; ++dt) o4[mt][dt][r] *= sc;
      }

    // ---- PV ----  (P is wave-private; no barrier needed)
    f16x8 pa[2][2], vbf[2][2];
#pragma unroll
    for (int mt = 0; mt < 2; ++mt)
#pragma unroll
      for (int hf = 0; hf < 2; ++hf)
        pa[mt][hf] = *(const f16x8*)&Ps[wave][mt * 16 + c][hf * 32 + g * 8];
#pragma unroll
    for (int dt = 0; dt < 2; ++dt)
#pragma unroll
      for (int hf = 0; hf < 2; ++hf)
        vbf[dt][hf] = *(const f16x8*)&Vt[dt * 16 + c][hf * 32 + g * 8];
#pragma unroll
    for (int mt = 0; mt < 2; ++mt)
#pragma unroll
      for (int dt = 0; dt < 2; ++dt) {
        o4[mt][dt] = __builtin_amdgcn_mfma_f32_16x16x32_f16(pa[mt][0], vbf[dt][0], o4[mt][dt], 0, 0, 0);
        o4[mt][dt] = __builtin_amdgcn_mfma_f32_16x16x32_f16(pa[mt][1], vbf[dt][1], o4[mt][dt], 0, 0, 0);
      }
  }

  // ---- epilogue ----
  const int h = bh & 3;
#pragma unroll
  for (int mt = 0; mt < 2; ++mt) {
    float rdiv[4];
#pragma unroll
    for (int r = 0; r < 4; ++r) rdiv[r] = 1.f / l[mt][r];
#pragma unroll
    for (int dt = 0; dt < 2; ++dt)
#pragma unroll
      for (int r = 0; r < 4; ++r) {
        const int row = qw + mt * 16 + g * 4 + r;
        o[((size_t)b * LL + row) * DD + h * DKK + dt * 16 + c] =
            o4[mt][dt][r] * rdiv[r];
      }
  }
}

// ---------------- output projection + residual ----------------
__global__ __launch_bounds__(256) void oproj_kernel(
    const float* __restrict__ o, const float* __restrict__ x,
    const float* __restrict__ Wo, float* __restrict__ xmid) {
  __shared__ float os[16][128];
  const int t = threadIdx.x;
  const long r0 = (long)blockIdx.x * 16;
  for (int idx = t; idx < 2048; idx += 256)
    os[idx >> 7][idx & 127] = o[r0 * 128 + idx];
  __syncthreads();
  const int jj = t & 127, rh = t >> 7;
  float acc[8];
#pragma unroll
  for (int r = 0; r < 8; ++r) acc[r] = 0.f;
  for (int d = 0; d < 128; ++d) {
    const float w = Wo[d * 128 + jj];
#pragma unroll
    for (int r = 0; r < 8; ++r) acc[r] += os[rh * 8 + r][d] * w;
  }
#pragma unroll
  for (int r = 0; r < 8; ++r) {
    const long gr = r0 + rh * 8 + r;
    xmid[gr * 128 + jj] = (acc[r] + x[gr * 128 + jj]) * 0.5f;
  }
}

// ---------------- FFN layer 1 + exact GELU ----------------
__global__ __launch_bounds__(256) void ffn1_kernel(
    const float* __restrict__ xmid, const float* __restrict__ W1,
    const float* __restrict__ b1, float* __restrict__ f) {
  __shared__ float xs[16][128];
  const int t = threadIdx.x;
  const long r0 = (long)blockIdx.x * 16;
  for (int idx = t; idx < 2048; idx += 256)
    xs[idx >> 7][idx & 127] = xmid[r0 * 128 + idx];
  __syncthreads();
  float acc[16];
#pragma unroll
  for (int r = 0; r < 16; ++r) acc[r] = 0.f;
  for (int d = 0; d < 128; ++d) {
    const float w = W1[d * 256 + t];
#pragma unroll
    for (int r = 0; r < 16; ++r) acc[r] += xs[r][d] * w;
  }
  const float bj = b1[t];
#pragma unroll
  for (int r = 0; r < 16; ++r) {
    const float val = acc[r] + bj;
    const float g = 0.5f * val * (1.f + erff(val * 0.70710678118654752f));
    f[(r0 + r) * 256 + t] = g;
  }
}

// ---------------- FFN layer 2 + bias + residual ----------------
__global__ __launch_bounds__(256) void ffn2_kernel(
    const float* __restrict__ f, const float* __restrict__ xmid,
    const float* __restrict__ W2, const float* __restrict__ b2,
    float* __restrict__ xout) {
  __shared__ float fs[16][256];
  const int t = threadIdx.x;
  const long r0 = (long)blockIdx.x * 16;
  for (int idx = t; idx < 4096; idx += 256)
    fs[idx >> 8][idx & 255] = f[r0 * 256 + idx];
  __syncthreads();
  const int jj = t & 127, rh = t >> 7;
  float acc[8];
#pragma unroll
  for (int r = 0; r < 8; ++r) acc[r] = 0.f;
  for (int d = 0; d < 256; ++d) {
    const float w = W2[d * 128 + jj];
#pragma unroll
    for (int r = 0; r < 8; ++r) acc[r] += fs[rh * 8 + r][d] * w;
  }
  const float bj = b2[jj];
#pragma unroll
  for (int r = 0; r < 8; ++r) {
    const long gr = r0 + rh * 8 + r;
    xout[gr * 128 + jj] = (acc[r] + bj + xmid[gr * 128 + jj]) * 0.5f;
  }
}

extern "C" void kernel_launch(void* const* d_in, const int* in_sizes, int n_in,
                              void* d_out, int out_size, void* d_ws,
                              size_t ws_size, hipStream_t stream) {
  const float* x    = (const float*)d_in[0];
  const float* mask = (const float*)d_in[1];
  const float* Wq   = (const float*)d_in[2];
  const float* Wk   = (const float*)d_in[3];
  const float* Wv   = (const float*)d_in[4];
  const float* Wo   = (const float*)d_in[5];
  const float* W1   = (const float*)d_in[6];
  const float* b1   = (const float*)d_in[7];
  const float* W2   = (const float*)d_in[8];
  const float* b2   = (const float*)d_in[9];

  const size_t SZ = (size_t)BB * LL * DD;   // 2,097,152
  char* p = (char*)d_ws;
  f16* qh   = (f16*)p;  p += SZ * sizeof(f16);
  f16* kh   = (f16*)p;  p += SZ * sizeof(f16);
  f16* vth  = (f16*)p;  p += SZ * sizeof(f16);
  float* ob   = (float*)p;  p += SZ * sizeof(float);
  float* xmid = (float*)p;  p += SZ * sizeof(float);
  float* fb   = (float*)p;  p += 2 * SZ * sizeof(float);
  float* xA   = (float*)p;

  const int M = BB * LL;       // 16384 rows
  const int rowBlocks = M / 16;

  for (int i = 0; i < 2; ++i) {
    const float* xin = (i == 0) ? x : xA;
    float* xout = (i == 1) ? (float*)d_out : xA;
    const float* Wq_i = Wq + (long)i * HH * DD * DKK;
    const float* Wk_i = Wk + (long)i * HH * DD * DKK;
    const float* Wv_i = Wv + (long)i * HH * DD * DKK;
    const float* Wo_i = Wo + (long)i * DD * DD;
    const float* W1_i = W1 + (long)i * DD * DFFF;
    const float* b1_i = b1 + (long)i * DFFF;
    const float* W2_i = W2 + (long)i * DFFF * DD;
    const float* b2_i = b2 + (long)i * DD;

    qkv_kernel<<<rowBlocks, 384, 0, stream>>>(xin, Wq_i, Wk_i, Wv_i, qh, kh, vth);
    attn_kernel<<<dim3(LL / 128, BB * HH), 256, 0, stream>>>(qh, kh, vth, mask, ob);
    oproj_kernel<<<rowBlocks, 256, 0, stream>>>(ob, xin, Wo_i, xmid);
    ffn1_kernel<<<rowBlocks, 256, 0, stream>>>(xmid, W1_i, b1_i, fb);
    ffn2_kernel<<<rowBlocks, 256, 0, stream>>>(fb, xmid, W2_i, b2_i, xout);
  }
}